// Round 13
// baseline (929.689 us; speedup 1.0000x reference)
//
#include <hip/hip_runtime.h>
#include <hip/hip_bf16.h>
#include <math.h>

// Problem constants
constexpr int Bv  = 4;
constexpr int Lv  = 2048;
constexpr int DM  = 258;            // d_model
constexpr int NL  = 4;              // layers
constexpr int DS  = 16;             // d_state
constexpr int DC  = 4;              // d_conv
constexpr int DI  = 516;            // d_inner
constexpr int DTR = 17;             // dt_rank
constexpr int TOK = Bv*Lv;          // 8192
constexpr float EPS = 1e-5f;

// padded dims
constexpr int DMp = 288;    // in_proj K pad; x / xn row stride
constexpr int N1p = 1152;   // in_proj N pad; xz row stride
constexpr int DIp = 544;    // out_proj K pad; xi_b / y row stride
constexpr int XDp = 128;    // x_proj N pad; xdbl row stride
constexpr int N3p = 384;    // out_proj N pad
constexpr int DIc = 520;    // scan channel pad (pad channels clamped; outputs killed downstream)

// chunked scan params
constexpr int CT  = 8;              // chunk length (16->8: doubles block parallelism)
constexpr int NC  = Lv / CT;        // 256 chunks per sequence
constexpr int NCB = Bv * NC;        // 1024 (b,chunk) pairs -> ~3 blocks/CU resident
constexpr int SCT = 576;            // scan block threads (9 waves; covers DIc=520)
constexpr int NCH = 128;            // combine: chunks per half-tile

// LDS row layout for staged xdbl rows: [0..16]=dt_lo, [20..35]=B, [36..51]=C
constexpr int LROW = 52;

typedef __bf16 bf16x8 __attribute__((ext_vector_type(8)));
typedef float  floatx4 __attribute__((ext_vector_type(4)));

#if defined(__has_builtin)
#if __has_builtin(__builtin_amdgcn_global_load_lds)
#define USE_ASYNC_LDS 1
#endif
#endif

// ---------------- weight convert + pad: f32 [L][N][K] -> bf16 [L][Np][Kp] ----------------
__global__ void cvt_pad_kernel(__hip_bfloat16* __restrict__ dst, const float* __restrict__ src,
                               int N, int K, int Np, int Kp, int total) {
    int idx = blockIdx.x*256 + threadIdx.x;
    if (idx >= total) return;
    int k = idx % Kp; int t = idx / Kp; int n = t % Np; int l = t / Np;
    float v = (n < N && k < K) ? src[((size_t)l*N + n)*K + k] : 0.f;
    dst[idx] = __float2bfloat16(v);
}

// ---------------- zero bf16 pad columns of xi_b and y ----------------
__global__ void zero_pads_kernel(__hip_bfloat16* __restrict__ xi_b, __hip_bfloat16* __restrict__ y) {
    constexpr int PAD = DIp - DI;   // 28
    int idx = blockIdx.x*256 + threadIdx.x;
    if (idx >= 2*TOK*PAD) return;
    int c = idx % PAD; int t = idx / PAD; int row = t % TOK; int sel = t / TOK;
    __hip_bfloat16* buf = sel ? y : xi_b;
    buf[(size_t)row*DIp + DI + c] = __float2bfloat16(0.f);
}

// ---------------- rmsnorm -> bf16 padded [TOK][DMp] ----------------
__global__ void rmsnorm_kernel(__hip_bfloat16* __restrict__ out, const float* __restrict__ x,
                               int ldx, const float* __restrict__ w) {
    int tok = blockIdx.x;
    const float* xr = x + (size_t)tok*ldx;
    int t = threadIdx.x;
    float v0 = xr[t];
    float v1 = (t < DM-256) ? xr[256+t] : 0.f;
    float ss = v0*v0 + v1*v1;
    for (int o = 32; o; o >>= 1) ss += __shfl_down(ss, o, 64);
    __shared__ float red[4];
    int wid = t >> 6, lane = t & 63;
    if (lane == 0) red[wid] = ss;
    __syncthreads();
    float tot = red[0]+red[1]+red[2]+red[3];
    float r = rsqrtf(tot/(float)DM + EPS);
    __hip_bfloat16* outr = out + (size_t)tok*DMp;
    outr[t] = __float2bfloat16(v0*r*w[t]);
    if (t < DM-256) outr[256+t] = __float2bfloat16(v1*r*w[256+t]);
    else if (t < DMp-256) outr[256+t] = __float2bfloat16(0.f);
}

// ---------------- final: out = fuse + rmsnorm(x, w) ----------------
__global__ void final_kernel(float* __restrict__ out, const float* __restrict__ x,
                             const float* __restrict__ fuse, const float* __restrict__ w) {
    int tok = blockIdx.x;
    const float* xr = x + (size_t)tok*DMp;
    const float* fr = fuse + (size_t)tok*DM;
    int t = threadIdx.x;
    float v0 = xr[t];
    float v1 = (t < DM-256) ? xr[256+t] : 0.f;
    float ss = v0*v0 + v1*v1;
    for (int o = 32; o; o >>= 1) ss += __shfl_down(ss, o, 64);
    __shared__ float red[4];
    int wid = t >> 6, lane = t & 63;
    if (lane == 0) red[wid] = ss;
    __syncthreads();
    float tot = red[0]+red[1]+red[2]+red[3];
    float r = rsqrtf(tot/(float)DM + EPS);
    float* outr = out + (size_t)tok*DM;
    outr[t] = fr[t] + v0*r*w[t];
    if (t < DM-256) outr[256+t] = fr[256+t] + v1*r*w[256+t];
}

// ---------------- bf16 MFMA NT-GEMM ----------------
__global__ __launch_bounds__(256) void gemm_bf16(
    const __hip_bfloat16* __restrict__ A, int lda,
    const __hip_bfloat16* __restrict__ B, int ldb,
    float* __restrict__ C, int ldc, int nstore,
    const float* __restrict__ resid, int ldr, int K) {
    __shared__ unsigned short Asm[128*32];
    __shared__ unsigned short Bsm[128*32];
    int tid = threadIdx.x;
    int w = tid >> 6, lane = tid & 63;
    int row0 = blockIdx.y * 128, col0 = blockIdx.x * 128;

    int srow = lane >> 2;
    int scol = (lane & 3) * 8;

    const __hip_bfloat16* Ag = A + (size_t)(row0 + w*32 + srow)*lda + scol;
    const __hip_bfloat16* Bg = B + (size_t)(col0 + w*32 + srow)*ldb + scol;

    int wr = (w >> 1) * 64, wc = (w & 1) * 64;
    int fr_row = lane & 15;
    int fr_k   = (lane >> 4) * 8;

    floatx4 acc[4][4];
    #pragma unroll
    for (int i = 0; i < 4; i++)
        #pragma unroll
        for (int j = 0; j < 4; j++)
            acc[i][j] = (floatx4){0.f, 0.f, 0.f, 0.f};

    for (int k0 = 0; k0 < K; k0 += 32) {
#ifdef USE_ASYNC_LDS
        __builtin_amdgcn_global_load_lds(
            (const __attribute__((address_space(1))) unsigned int*)Ag,
            (__attribute__((address_space(3))) unsigned int*)&Asm[(w*32)*32], 16, 0, 0);
        __builtin_amdgcn_global_load_lds(
            (const __attribute__((address_space(1))) unsigned int*)(Ag + 16*lda),
            (__attribute__((address_space(3))) unsigned int*)&Asm[(w*32+16)*32], 16, 0, 0);
        __builtin_amdgcn_global_load_lds(
            (const __attribute__((address_space(1))) unsigned int*)Bg,
            (__attribute__((address_space(3))) unsigned int*)&Bsm[(w*32)*32], 16, 0, 0);
        __builtin_amdgcn_global_load_lds(
            (const __attribute__((address_space(1))) unsigned int*)(Bg + 16*ldb),
            (__attribute__((address_space(3))) unsigned int*)&Bsm[(w*32+16)*32], 16, 0, 0);
#else
        {
            int4 va0 = *(const int4*)Ag;
            int4 va1 = *(const int4*)(Ag + 16*lda);
            int4 vb0 = *(const int4*)Bg;
            int4 vb1 = *(const int4*)(Bg + 16*ldb);
            *(int4*)&Asm[(w*32 + srow)*32 + scol]      = va0;
            *(int4*)&Asm[(w*32 + 16 + srow)*32 + scol] = va1;
            *(int4*)&Bsm[(w*32 + srow)*32 + scol]      = vb0;
            *(int4*)&Bsm[(w*32 + 16 + srow)*32 + scol] = vb1;
        }
#endif
        Ag += 32; Bg += 32;
        __syncthreads();

        bf16x8 af[4], bfr[4];
        #pragma unroll
        for (int rb = 0; rb < 4; rb++)
            af[rb] = *(const bf16x8*)&Asm[(wr + rb*16 + fr_row)*32 + fr_k];
        #pragma unroll
        for (int cb = 0; cb < 4; cb++)
            bfr[cb] = *(const bf16x8*)&Bsm[(wc + cb*16 + fr_row)*32 + fr_k];
        #pragma unroll
        for (int rb = 0; rb < 4; rb++)
            #pragma unroll
            for (int cb = 0; cb < 4; cb++)
                acc[rb][cb] = __builtin_amdgcn_mfma_f32_16x16x32_bf16(
                    af[rb], bfr[cb], acc[rb][cb], 0, 0, 0);
        __syncthreads();
    }

    #pragma unroll
    for (int rb = 0; rb < 4; rb++) {
        int gm0 = row0 + wr + rb*16 + (lane >> 4)*4;
        #pragma unroll
        for (int cb = 0; cb < 4; cb++) {
            int gn = col0 + wc + cb*16 + (lane & 15);
            if (gn < nstore) {
                #pragma unroll
                for (int r = 0; r < 4; r++) {
                    float v = acc[rb][cb][r];
                    if (resid) v += resid[(size_t)(gm0 + r)*ldr + gn];
                    C[(size_t)(gm0 + r)*ldc + gn] = v;
                }
            }
        }
    }
}

// ---------------- causal depthwise conv (k=4) + silu ----------------
__global__ void conv_silu_kernel(float* __restrict__ xi_f, __hip_bfloat16* __restrict__ xi_b,
                                 const float* __restrict__ xz,
                                 const float* __restrict__ cw, const float* __restrict__ cb) {
    int idx = blockIdx.x*256 + threadIdx.x;
    if (idx >= TOK*DI) return;
    int d = idx % DI, tok = idx / DI;
    int l = tok % Lv;
    float acc = cb[d];
    #pragma unroll
    for (int j = 0; j < DC; j++) {
        int lj = l - (DC-1) + j;
        if (lj >= 0)
            acc += xz[(size_t)(tok - (DC-1) + j)*N1p + d] * cw[d*DC + j];
    }
    float s = acc / (1.f + __expf(-acc));
    xi_f[(size_t)tok*DI + d] = s;
    xi_b[(size_t)tok*DIp + d] = __float2bfloat16(s);
}

// ================= chunked parallel scan =================
__device__ __forceinline__ void stage_xdbl(float* xb, const float* __restrict__ xdbl,
                                           size_t tok0, int tid, int nthr) {
    for (int idx = tid; idx < CT*49; idx += nthr) {
        int t = idx / 49, c2 = idx % 49;
        int dst = c2 + (c2 >= DTR ? 3 : 0);     // B at 20, C at 36 (16B aligned)
        xb[t*LROW + dst] = xdbl[(tok0 + t)*XDp + c2];
    }
}

// Pass 1: local scan from h=0; stores dt, sum(dt), final local h[16].
__global__ __launch_bounds__(SCT) void scan_chunk3(
    const float* __restrict__ xi, const float* __restrict__ xdbl,
    const float* __restrict__ A_log, const float* __restrict__ dtw,
    const float* __restrict__ dtb, float* __restrict__ dtbuf,
    float* __restrict__ sumdt_ws, float* __restrict__ H_ws) {
    __shared__ __attribute__((aligned(16))) float xb[CT*LROW];
    int tid = threadIdx.x;
    int bc = blockIdx.x;                 // 0..NCB-1
    int b = bc / NC, c = bc % NC;
    size_t tok0 = (size_t)b*Lv + (size_t)c*CT;
    stage_xdbl(xb, xdbl, tok0, tid, SCT);
    __syncthreads();
    int d = tid;                          // 0..575
    if (d >= DIc) return;
    int dp_ = d < DI ? d : DI-1;          // clamp pad channels

    float a[DS];
    const float* ap = A_log + (size_t)dp_*DS;
    #pragma unroll
    for (int s = 0; s < DS; s++) a[s] = -__expf(ap[s]);
    float w17[DTR];
    #pragma unroll
    for (int r = 0; r < DTR; r++) w17[r] = dtw[dp_*DTR + r];
    float dtbv = dtb[dp_];

    float h[DS];
    #pragma unroll
    for (int s = 0; s < DS; s++) h[s] = 0.f;
    float sdt = 0.f;
    #pragma unroll 2
    for (int t = 0; t < CT; t++) {
        const float* row = xb + t*LROW;
        float u = xi[(tok0 + t)*DI + dp_];
        float4 q0 = *(const float4*)(row);
        float4 q1 = *(const float4*)(row+4);
        float4 q2 = *(const float4*)(row+8);
        float4 q3 = *(const float4*)(row+12);
        float acc = fmaf(row[16], w17[16], dtbv);
        acc = fmaf(q0.x, w17[0], acc);  acc = fmaf(q0.y, w17[1], acc);
        acc = fmaf(q0.z, w17[2], acc);  acc = fmaf(q0.w, w17[3], acc);
        acc = fmaf(q1.x, w17[4], acc);  acc = fmaf(q1.y, w17[5], acc);
        acc = fmaf(q1.z, w17[6], acc);  acc = fmaf(q1.w, w17[7], acc);
        acc = fmaf(q2.x, w17[8], acc);  acc = fmaf(q2.y, w17[9], acc);
        acc = fmaf(q2.z, w17[10], acc); acc = fmaf(q2.w, w17[11], acc);
        acc = fmaf(q3.x, w17[12], acc); acc = fmaf(q3.y, w17[13], acc);
        acc = fmaf(q3.z, w17[14], acc); acc = fmaf(q3.w, w17[15], acc);
        float dtv = fmaxf(acc, 0.f) + log1pf(__expf(-fabsf(acc)));
        dtbuf[(tok0 + t)*DIc + d] = dtv;
        float du = dtv * u;
        sdt += dtv;
        float Bl[DS];
        *(float4*)&Bl[0]  = *(const float4*)(row+20);
        *(float4*)&Bl[4]  = *(const float4*)(row+24);
        *(float4*)&Bl[8]  = *(const float4*)(row+28);
        *(float4*)&Bl[12] = *(const float4*)(row+32);
        #pragma unroll
        for (int s = 0; s < DS; s++)
            h[s] = fmaf(__expf(dtv*a[s]), h[s], du*Bl[s]);
    }
    size_t cc = (size_t)bc*DIc + d;
    sumdt_ws[cc] = sdt;
    float* Hp = H_ws + cc*DS;
    #pragma unroll
    for (int s = 0; s < DS; s++) Hp[s] = h[s];
}

// Pass 2: LDS-transpose combine over NC=256 chunks, processed as two halves of
// 128 with per-row register carry. IN-PLACE: hinit overwrites H_ws (each half's
// tile is fully loaded to LDS before its stores; halves are disjoint).
constexpr int RD = 4;   // d-channels per combine block
__global__ __launch_bounds__(256) void scan_combine_lds(
    const float* __restrict__ sumdt_ws, float* __restrict__ H_ws,
    const float* __restrict__ A_log) {
    __shared__ float tile[RD*DS][NCH+1];
    __shared__ float sd[RD][NCH+1];
    int tid = threadIdx.x;
    int b = blockIdx.y;
    int d0 = blockIdx.x * RD;             // 0..516 step 4 (DIc/RD = 130 blocks)
    int lane = tid & 63, w = tid >> 6;

    float aval[16], carry[16];
    #pragma unroll
    for (int rr = 0; rr < 16; rr++) {
        int row = w*16 + rr;
        int dd = row >> 4, s = row & 15;
        int dcl = (d0 + dd < DI) ? d0 + dd : DI-1;
        aval[rr] = -__expf(A_log[dcl*DS + s]);
        carry[rr] = 0.f;
    }

    for (int half = 0; half < NC/NCH; half++) {
        int cbase = half*NCH;
        __syncthreads();   // separate from previous half's store phase
        for (int r = 0; r < NCH/4; r++) {
            int c = r*4 + (tid >> 6);
            int j = tid & 63;
            tile[j][c] = H_ws[((size_t)(b*NC + cbase + c)*DIc + d0)*DS + j];
        }
        for (int idx = tid; idx < RD*NCH; idx += 256) {
            int c = idx >> 2, dd = idx & 3;
            sd[dd][c] = sumdt_ws[(size_t)(b*NC + cbase + c)*DIc + d0 + dd];
        }
        __syncthreads();
        for (int rr = 0; rr < 16; rr++) {
            int row = w*16 + rr;
            int dd = row >> 4;
            float a = aval[rr];
            float cr = carry[rr];
            #pragma unroll
            for (int seg = 0; seg < NCH/64; seg++) {
                int c = seg*64 + lane;
                float g = __expf(a * sd[dd][c]);
                float H = tile[row][c];
                #pragma unroll
                for (int off = 1; off < 64; off <<= 1) {
                    float gp = __shfl_up(g, off);
                    float Hp = __shfl_up(H, off);
                    if (lane >= off) { H = fmaf(g, Hp, H); g *= gp; }
                }
                float Gx = (lane == 0) ? 1.f : __shfl_up(g, 1);
                float Hx = (lane == 0) ? 0.f : __shfl_up(H, 1);
                tile[row][c] = fmaf(Gx, cr, Hx);   // hinit for chunk cbase+c
                float Gl = __shfl(g, 63), Hl = __shfl(H, 63);
                cr = fmaf(Gl, cr, Hl);
            }
            carry[rr] = cr;
        }
        __syncthreads();
        for (int r = 0; r < NCH/4; r++) {
            int c = r*4 + (tid >> 6);
            int j = tid & 63;
            H_ws[((size_t)(b*NC + cbase + c)*DIc + d0)*DS + j] = tile[j][c];
        }
    }
}

// Pass 3: re-scan chunk from hinit (= rewritten H_ws), fused epilogue.
__global__ __launch_bounds__(SCT) void scan_final3(
    const float* __restrict__ xi, const float* __restrict__ xdbl,
    const float* __restrict__ xz, const float* __restrict__ A_log,
    const float* __restrict__ dtbuf, const float* __restrict__ Dp,
    const float* __restrict__ hinit_ws, __hip_bfloat16* __restrict__ y) {
    __shared__ __attribute__((aligned(16))) float xb[CT*LROW];
    int tid = threadIdx.x;
    int bc = blockIdx.x;
    int b = bc / NC, c = bc % NC;
    size_t tok0 = (size_t)b*Lv + (size_t)c*CT;
    stage_xdbl(xb, xdbl, tok0, tid, SCT);
    __syncthreads();
    int d = tid;
    if (d >= DIc) return;
    int dp_ = d < DI ? d : DI-1;

    float a[DS];
    const float* ap = A_log + (size_t)dp_*DS;
    #pragma unroll
    for (int s = 0; s < DS; s++) a[s] = -__expf(ap[s]);
    float Dv = Dp[dp_];

    float h[DS];
    const float* hp = hinit_ws + ((size_t)bc*DIc + d)*DS;
    #pragma unroll
    for (int s = 0; s < DS; s++) h[s] = hp[s];

    #pragma unroll 2
    for (int t = 0; t < CT; t++) {
        const float* row = xb + t*LROW;
        size_t tok = tok0 + t;
        float u   = xi[tok*DI + dp_];
        float zv  = xz[tok*N1p + DI + d];
        float dtv = dtbuf[tok*DIc + d];
        float du = dtv * u;
        float Bl[DS], Cl[DS];
        *(float4*)&Bl[0]  = *(const float4*)(row+20);
        *(float4*)&Bl[4]  = *(const float4*)(row+24);
        *(float4*)&Bl[8]  = *(const float4*)(row+28);
        *(float4*)&Bl[12] = *(const float4*)(row+32);
        *(float4*)&Cl[0]  = *(const float4*)(row+36);
        *(float4*)&Cl[4]  = *(const float4*)(row+40);
        *(float4*)&Cl[8]  = *(const float4*)(row+44);
        *(float4*)&Cl[12] = *(const float4*)(row+48);
        float yv0 = 0.f, yv1 = 0.f;
        #pragma unroll
        for (int s = 0; s < DS; s += 2) {
            h[s]   = fmaf(__expf(dtv*a[s]),   h[s],   du*Bl[s]);
            h[s+1] = fmaf(__expf(dtv*a[s+1]), h[s+1], du*Bl[s+1]);
            yv0 = fmaf(h[s],   Cl[s],   yv0);
            yv1 = fmaf(h[s+1], Cl[s+1], yv1);
        }
        float yv = yv0 + yv1 + u*Dv;
        float g = zv / (1.f + __expf(-zv));
        y[tok*DIp + d] = __float2bfloat16(yv * g);
    }
}

extern "C" void kernel_launch(void* const* d_in, const int* in_sizes, int n_in,
                              void* d_out, int out_size, void* d_ws, size_t ws_size,
                              hipStream_t stream) {
    const float* fuse   = (const float*)d_in[0];
    const float* norm_w = (const float*)d_in[1];
    const float* in_w   = (const float*)d_in[2];
    const float* conv_w = (const float*)d_in[3];
    const float* conv_b = (const float*)d_in[4];
    const float* xp_w   = (const float*)d_in[5];
    const float* dt_w   = (const float*)d_in[6];
    const float* dt_b   = (const float*)d_in[7];
    const float* A_log  = (const float*)d_in[8];
    const float* D_par  = (const float*)d_in[9];
    const float* out_w  = (const float*)d_in[10];
    const float* fn_w   = (const float*)d_in[11];

    char* p = (char*)d_ws;
    auto alloc = [&](size_t bytes) { char* r = p; p += (bytes + 255) & ~(size_t)255; return r; };

    float*          x     = (float*)         alloc((size_t)TOK*DMp*4);
    __hip_bfloat16* xn    = (__hip_bfloat16*)alloc((size_t)TOK*DMp*2);
    float*          xz    = (float*)         alloc((size_t)TOK*N1p*4);
    float*          xi_f  = (float*)         alloc((size_t)TOK*DI*4);
    __hip_bfloat16* xi_b  = (__hip_bfloat16*)alloc((size_t)TOK*DIp*2);
    float*          xdbl  = (float*)         alloc((size_t)TOK*XDp*4);
    __hip_bfloat16* y     = (__hip_bfloat16*)alloc((size_t)TOK*DIp*2);
    float*          dtbuf = (float*)         alloc((size_t)TOK*DIc*4);
    float*          sumdt = (float*)         alloc((size_t)NCB*DIc*4);
    float*          Hws   = (float*)         alloc((size_t)NCB*DIc*DS*4);   // H, then hinit in-place
    __hip_bfloat16* W1b   = (__hip_bfloat16*)alloc((size_t)NL*N1p*DMp*2);
    __hip_bfloat16* W2b   = (__hip_bfloat16*)alloc((size_t)NL*XDp*DIp*2);
    __hip_bfloat16* W3b   = (__hip_bfloat16*)alloc((size_t)NL*N3p*DIp*2);

    {
        int t1 = NL*N1p*DMp, t2 = NL*XDp*DIp, t3 = NL*N3p*DIp;
        cvt_pad_kernel<<<(t1+255)/256, 256, 0, stream>>>(W1b, in_w, 2*DI, DM, N1p, DMp, t1);
        cvt_pad_kernel<<<(t2+255)/256, 256, 0, stream>>>(W2b, xp_w, DTR+2*DS, DI, XDp, DIp, t2);
        cvt_pad_kernel<<<(t3+255)/256, 256, 0, stream>>>(W3b, out_w, DM, DI, N3p, DIp, t3);
        int tz = 2*TOK*(DIp-DI);
        zero_pads_kernel<<<(tz+255)/256, 256, 0, stream>>>(xi_b, y);
    }

    for (int i = 0; i < NL; i++) {
        const __hip_bfloat16* w1 = W1b + (size_t)i*N1p*DMp;
        const __hip_bfloat16* w2 = W2b + (size_t)i*XDp*DIp;
        const __hip_bfloat16* w3 = W3b + (size_t)i*N3p*DIp;
        const float* cw   = conv_w + (size_t)i*DI*DC;
        const float* cb   = conv_b + (size_t)i*DI;
        const float* dtw  = dt_w   + (size_t)i*DI*DTR;
        const float* dtb  = dt_b   + (size_t)i*DI;
        const float* alog = A_log  + (size_t)i*DI*DS;
        const float* dp   = D_par  + (size_t)i*DI;
        const float* nw   = norm_w + (size_t)i*DM;
        const float* xcur = (i == 0) ? fuse : x;
        int ld_cur = (i == 0) ? DM : DMp;

        rmsnorm_kernel<<<TOK, 256, 0, stream>>>(xn, xcur, ld_cur, nw);
        gemm_bf16<<<dim3(N1p/128, TOK/128), 256, 0, stream>>>(
            xn, DMp, w1, DMp, xz, N1p, N1p, nullptr, 0, DMp);
        conv_silu_kernel<<<(TOK*DI + 255)/256, 256, 0, stream>>>(xi_f, xi_b, xz, cw, cb);
        gemm_bf16<<<dim3(XDp/128, TOK/128), 256, 0, stream>>>(
            xi_b, DIp, w2, DIp, xdbl, XDp, XDp, nullptr, 0, DIp);
        // chunked parallel scan (CT=8: ~3 blocks/CU; in-place combine)
        scan_chunk3<<<NCB, SCT, 0, stream>>>(xi_f, xdbl, alog, dtw, dtb, dtbuf, sumdt, Hws);
        scan_combine_lds<<<dim3(DIc/RD, Bv), 256, 0, stream>>>(sumdt, Hws, alog);
        scan_final3<<<NCB, SCT, 0, stream>>>(xi_f, xdbl, xz, alog, dtbuf, dp, Hws, y);
        gemm_bf16<<<dim3(N3p/128, TOK/128), 256, 0, stream>>>(
            y, DIp, w3, DIp, x, DMp, DM, xcur, ld_cur, DIp);
    }

    final_kernel<<<TOK, 256, 0, stream>>>((float*)d_out, x, fuse, fn_w);
}

// Round 14
// 852.365 us; speedup vs baseline: 1.0907x; 1.0907x over previous
//
#include <hip/hip_runtime.h>
#include <hip/hip_bf16.h>
#include <math.h>

// Problem constants
constexpr int Bv  = 4;
constexpr int Lv  = 2048;
constexpr int DM  = 258;            // d_model
constexpr int NL  = 4;              // layers
constexpr int DS  = 16;             // d_state
constexpr int DC  = 4;              // d_conv
constexpr int DI  = 516;            // d_inner
constexpr int DTR = 17;             // dt_rank
constexpr int TOK = Bv*Lv;          // 8192
constexpr float EPS = 1e-5f;

// padded dims
constexpr int DMp = 288;    // in_proj K pad; x / xn row stride
constexpr int N1p = 1152;   // in_proj N pad; xz row stride
constexpr int DIp = 544;    // out_proj K pad; xi_b / y row stride
constexpr int XDp = 128;    // x_proj N pad; xdbl row stride
constexpr int N3p = 384;    // out_proj N pad
constexpr int DIc = 520;    // scan channel pad (pad channels clamped; outputs killed downstream)

// chunked scan params
constexpr int CT  = 16;             // chunk length
constexpr int NC  = Lv / CT;        // 128 chunks per sequence
constexpr int NCB = Bv * NC;        // 512 (b,chunk) pairs
constexpr int SCT = 576;            // scan block threads (9 waves; covers DIc=520)

// LDS row layout for staged xdbl rows: [0..16]=dt_lo, [20..35]=B, [36..51]=C
// (row base 208 B = 13*16 -> offsets 0,4,8,12,20,36 etc. all 16B-aligned)
constexpr int LROW = 52;

typedef __bf16 bf16x8 __attribute__((ext_vector_type(8)));
typedef float  floatx4 __attribute__((ext_vector_type(4)));

#if defined(__has_builtin)
#if __has_builtin(__builtin_amdgcn_global_load_lds)
#define USE_ASYNC_LDS 1
#endif
#endif

// ---------------- weight convert + pad: f32 [L][N][K] -> bf16 [L][Np][Kp] ----------------
__global__ void cvt_pad_kernel(__hip_bfloat16* __restrict__ dst, const float* __restrict__ src,
                               int N, int K, int Np, int Kp, int total) {
    int idx = blockIdx.x*256 + threadIdx.x;
    if (idx >= total) return;
    int k = idx % Kp; int t = idx / Kp; int n = t % Np; int l = t / Np;
    float v = (n < N && k < K) ? src[((size_t)l*N + n)*K + k] : 0.f;
    dst[idx] = __float2bfloat16(v);
}

// ---------------- zero bf16 pad columns of xi_b and y ----------------
__global__ void zero_pads_kernel(__hip_bfloat16* __restrict__ xi_b, __hip_bfloat16* __restrict__ y) {
    constexpr int PAD = DIp - DI;   // 28
    int idx = blockIdx.x*256 + threadIdx.x;
    if (idx >= 2*TOK*PAD) return;
    int c = idx % PAD; int t = idx / PAD; int row = t % TOK; int sel = t / TOK;
    __hip_bfloat16* buf = sel ? y : xi_b;
    buf[(size_t)row*DIp + DI + c] = __float2bfloat16(0.f);
}

// ---------------- rmsnorm -> bf16 padded [TOK][DMp] ----------------
__global__ void rmsnorm_kernel(__hip_bfloat16* __restrict__ out, const float* __restrict__ x,
                               int ldx, const float* __restrict__ w) {
    int tok = blockIdx.x;
    const float* xr = x + (size_t)tok*ldx;
    int t = threadIdx.x;
    float v0 = xr[t];
    float v1 = (t < DM-256) ? xr[256+t] : 0.f;
    float ss = v0*v0 + v1*v1;
    for (int o = 32; o; o >>= 1) ss += __shfl_down(ss, o, 64);
    __shared__ float red[4];
    int wid = t >> 6, lane = t & 63;
    if (lane == 0) red[wid] = ss;
    __syncthreads();
    float tot = red[0]+red[1]+red[2]+red[3];
    float r = rsqrtf(tot/(float)DM + EPS);
    __hip_bfloat16* outr = out + (size_t)tok*DMp;
    outr[t] = __float2bfloat16(v0*r*w[t]);
    if (t < DM-256) outr[256+t] = __float2bfloat16(v1*r*w[256+t]);
    else if (t < DMp-256) outr[256+t] = __float2bfloat16(0.f);
}

// ---------------- final: out = fuse + rmsnorm(x, w) ----------------
__global__ void final_kernel(float* __restrict__ out, const float* __restrict__ x,
                             const float* __restrict__ fuse, const float* __restrict__ w) {
    int tok = blockIdx.x;
    const float* xr = x + (size_t)tok*DMp;
    const float* fr = fuse + (size_t)tok*DM;
    int t = threadIdx.x;
    float v0 = xr[t];
    float v1 = (t < DM-256) ? xr[256+t] : 0.f;
    float ss = v0*v0 + v1*v1;
    for (int o = 32; o; o >>= 1) ss += __shfl_down(ss, o, 64);
    __shared__ float red[4];
    int wid = t >> 6, lane = t & 63;
    if (lane == 0) red[wid] = ss;
    __syncthreads();
    float tot = red[0]+red[1]+red[2]+red[3];
    float r = rsqrtf(tot/(float)DM + EPS);
    float* outr = out + (size_t)tok*DM;
    outr[t] = fr[t] + v0*r*w[t];
    if (t < DM-256) outr[256+t] = fr[256+t] + v1*r*w[256+t];
}

// ---------------- bf16 MFMA NT-GEMM ----------------
__global__ __launch_bounds__(256) void gemm_bf16(
    const __hip_bfloat16* __restrict__ A, int lda,
    const __hip_bfloat16* __restrict__ B, int ldb,
    float* __restrict__ C, int ldc, int nstore,
    const float* __restrict__ resid, int ldr, int K) {
    __shared__ unsigned short Asm[128*32];
    __shared__ unsigned short Bsm[128*32];
    int tid = threadIdx.x;
    int w = tid >> 6, lane = tid & 63;
    int row0 = blockIdx.y * 128, col0 = blockIdx.x * 128;

    int srow = lane >> 2;
    int scol = (lane & 3) * 8;

    const __hip_bfloat16* Ag = A + (size_t)(row0 + w*32 + srow)*lda + scol;
    const __hip_bfloat16* Bg = B + (size_t)(col0 + w*32 + srow)*ldb + scol;

    int wr = (w >> 1) * 64, wc = (w & 1) * 64;
    int fr_row = lane & 15;
    int fr_k   = (lane >> 4) * 8;

    floatx4 acc[4][4];
    #pragma unroll
    for (int i = 0; i < 4; i++)
        #pragma unroll
        for (int j = 0; j < 4; j++)
            acc[i][j] = (floatx4){0.f, 0.f, 0.f, 0.f};

    for (int k0 = 0; k0 < K; k0 += 32) {
#ifdef USE_ASYNC_LDS
        __builtin_amdgcn_global_load_lds(
            (const __attribute__((address_space(1))) unsigned int*)Ag,
            (__attribute__((address_space(3))) unsigned int*)&Asm[(w*32)*32], 16, 0, 0);
        __builtin_amdgcn_global_load_lds(
            (const __attribute__((address_space(1))) unsigned int*)(Ag + 16*lda),
            (__attribute__((address_space(3))) unsigned int*)&Asm[(w*32+16)*32], 16, 0, 0);
        __builtin_amdgcn_global_load_lds(
            (const __attribute__((address_space(1))) unsigned int*)Bg,
            (__attribute__((address_space(3))) unsigned int*)&Bsm[(w*32)*32], 16, 0, 0);
        __builtin_amdgcn_global_load_lds(
            (const __attribute__((address_space(1))) unsigned int*)(Bg + 16*ldb),
            (__attribute__((address_space(3))) unsigned int*)&Bsm[(w*32+16)*32], 16, 0, 0);
#else
        {
            int4 va0 = *(const int4*)Ag;
            int4 va1 = *(const int4*)(Ag + 16*lda);
            int4 vb0 = *(const int4*)Bg;
            int4 vb1 = *(const int4*)(Bg + 16*ldb);
            *(int4*)&Asm[(w*32 + srow)*32 + scol]      = va0;
            *(int4*)&Asm[(w*32 + 16 + srow)*32 + scol] = va1;
            *(int4*)&Bsm[(w*32 + srow)*32 + scol]      = vb0;
            *(int4*)&Bsm[(w*32 + 16 + srow)*32 + scol] = vb1;
        }
#endif
        Ag += 32; Bg += 32;
        __syncthreads();

        bf16x8 af[4], bfr[4];
        #pragma unroll
        for (int rb = 0; rb < 4; rb++)
            af[rb] = *(const bf16x8*)&Asm[(wr + rb*16 + fr_row)*32 + fr_k];
        #pragma unroll
        for (int cb = 0; cb < 4; cb++)
            bfr[cb] = *(const bf16x8*)&Bsm[(wc + cb*16 + fr_row)*32 + fr_k];
        #pragma unroll
        for (int rb = 0; rb < 4; rb++)
            #pragma unroll
            for (int cb = 0; cb < 4; cb++)
                acc[rb][cb] = __builtin_amdgcn_mfma_f32_16x16x32_bf16(
                    af[rb], bfr[cb], acc[rb][cb], 0, 0, 0);
        __syncthreads();
    }

    #pragma unroll
    for (int rb = 0; rb < 4; rb++) {
        int gm0 = row0 + wr + rb*16 + (lane >> 4)*4;
        #pragma unroll
        for (int cb = 0; cb < 4; cb++) {
            int gn = col0 + wc + cb*16 + (lane & 15);
            if (gn < nstore) {
                #pragma unroll
                for (int r = 0; r < 4; r++) {
                    float v = acc[rb][cb][r];
                    if (resid) v += resid[(size_t)(gm0 + r)*ldr + gn];
                    C[(size_t)(gm0 + r)*ldc + gn] = v;
                }
            }
        }
    }
}

// ---------------- causal depthwise conv (k=4) + silu ----------------
__global__ void conv_silu_kernel(float* __restrict__ xi_f, __hip_bfloat16* __restrict__ xi_b,
                                 const float* __restrict__ xz,
                                 const float* __restrict__ cw, const float* __restrict__ cb) {
    int idx = blockIdx.x*256 + threadIdx.x;
    if (idx >= TOK*DI) return;
    int d = idx % DI, tok = idx / DI;
    int l = tok % Lv;
    float acc = cb[d];
    #pragma unroll
    for (int j = 0; j < DC; j++) {
        int lj = l - (DC-1) + j;
        if (lj >= 0)
            acc += xz[(size_t)(tok - (DC-1) + j)*N1p + d] * cw[d*DC + j];
    }
    float s = acc / (1.f + __expf(-acc));
    xi_f[(size_t)tok*DI + d] = s;
    xi_b[(size_t)tok*DIp + d] = __float2bfloat16(s);
}

// ================= chunked parallel scan =================
__device__ __forceinline__ void stage_xdbl(float* xb, const float* __restrict__ xdbl,
                                           size_t tok0, int tid, int nthr) {
    for (int idx = tid; idx < CT*49; idx += nthr) {
        int t = idx / 49, c2 = idx % 49;
        int dst = c2 + (c2 >= DTR ? 3 : 0);     // B at 20, C at 36 (16B aligned)
        xb[t*LROW + dst] = xdbl[(tok0 + t)*XDp + c2];
    }
}

// Pass 1: local scan from h=0; stores dt, sum(dt), final local h[16].
// Vectorized ds_read_b128 row reads (5 LDS ops/t instead of 33).
__global__ __launch_bounds__(SCT) void scan_chunk3(
    const float* __restrict__ xi, const float* __restrict__ xdbl,
    const float* __restrict__ A_log, const float* __restrict__ dtw,
    const float* __restrict__ dtb, float* __restrict__ dtbuf,
    float* __restrict__ sumdt_ws, float* __restrict__ H_ws) {
    __shared__ __attribute__((aligned(16))) float xb[CT*LROW];
    int tid = threadIdx.x;
    int bc = blockIdx.x;                 // 0..NCB-1
    int b = bc / NC, c = bc % NC;
    size_t tok0 = (size_t)b*Lv + (size_t)c*CT;
    stage_xdbl(xb, xdbl, tok0, tid, SCT);
    __syncthreads();
    int d = tid;                          // 0..575
    if (d >= DIc) return;
    int dp_ = d < DI ? d : DI-1;          // clamp pad channels

    float a[DS];
    const float* ap = A_log + (size_t)dp_*DS;
    #pragma unroll
    for (int s = 0; s < DS; s++) a[s] = -__expf(ap[s]);
    float w17[DTR];
    #pragma unroll
    for (int r = 0; r < DTR; r++) w17[r] = dtw[dp_*DTR + r];
    float dtbv = dtb[dp_];

    float h[DS];
    #pragma unroll
    for (int s = 0; s < DS; s++) h[s] = 0.f;
    float sdt = 0.f;
    #pragma unroll 2
    for (int t = 0; t < CT; t++) {
        const float* row = xb + t*LROW;
        float u = xi[(tok0 + t)*DI + dp_];
        float4 q0 = *(const float4*)(row);
        float4 q1 = *(const float4*)(row+4);
        float4 q2 = *(const float4*)(row+8);
        float4 q3 = *(const float4*)(row+12);
        float acc = fmaf(row[16], w17[16], dtbv);
        acc = fmaf(q0.x, w17[0], acc);  acc = fmaf(q0.y, w17[1], acc);
        acc = fmaf(q0.z, w17[2], acc);  acc = fmaf(q0.w, w17[3], acc);
        acc = fmaf(q1.x, w17[4], acc);  acc = fmaf(q1.y, w17[5], acc);
        acc = fmaf(q1.z, w17[6], acc);  acc = fmaf(q1.w, w17[7], acc);
        acc = fmaf(q2.x, w17[8], acc);  acc = fmaf(q2.y, w17[9], acc);
        acc = fmaf(q2.z, w17[10], acc); acc = fmaf(q2.w, w17[11], acc);
        acc = fmaf(q3.x, w17[12], acc); acc = fmaf(q3.y, w17[13], acc);
        acc = fmaf(q3.z, w17[14], acc); acc = fmaf(q3.w, w17[15], acc);
        float dtv = fmaxf(acc, 0.f) + log1pf(__expf(-fabsf(acc)));
        dtbuf[(tok0 + t)*DIc + d] = dtv;
        float du = dtv * u;
        sdt += dtv;
        float Bl[DS];
        *(float4*)&Bl[0]  = *(const float4*)(row+20);
        *(float4*)&Bl[4]  = *(const float4*)(row+24);
        *(float4*)&Bl[8]  = *(const float4*)(row+28);
        *(float4*)&Bl[12] = *(const float4*)(row+32);
        #pragma unroll
        for (int s = 0; s < DS; s++)
            h[s] = fmaf(__expf(dtv*a[s]), h[s], du*Bl[s]);
    }
    size_t cc = (size_t)bc*DIc + d;
    sumdt_ws[cc] = sdt;
    float* Hp = H_ws + cc*DS;
    #pragma unroll
    for (int s = 0; s < DS; s++) Hp[s] = h[s];
}

// Pass 2: LDS-transpose combine. Block = (b, 4 d-channels); coalesced global
// access in [b][c][d][s] layout, wave-parallel shuffle scan over chunks.
constexpr int RD = 4;   // d-channels per combine block
__global__ __launch_bounds__(256) void scan_combine_lds(
    const float* __restrict__ sumdt_ws, const float* __restrict__ H_ws,
    const float* __restrict__ A_log, float* __restrict__ hinit_ws) {
    __shared__ float tile[RD*DS][NC+1];   // [(dd*16+s)][c], padded: conflict-free both phases
    __shared__ float sd[RD][NC+1];
    int tid = threadIdx.x;
    int b = blockIdx.y;
    int d0 = blockIdx.x * RD;             // 0..516 step 4 (DIc/RD = 130 blocks)
    for (int r = 0; r < NC/4; r++) {
        int c = r*4 + (tid >> 6);
        int j = tid & 63;
        tile[j][c] = H_ws[((size_t)(b*NC + c)*DIc + d0)*DS + j];
    }
    for (int idx = tid; idx < RD*NC; idx += 256) {
        int c = idx >> 2, dd = idx & 3;
        sd[dd][c] = sumdt_ws[(size_t)(b*NC + c)*DIc + d0 + dd];
    }
    __syncthreads();
    int lane = tid & 63, w = tid >> 6;
    for (int rr = 0; rr < 16; rr++) {
        int row = w*16 + rr;
        int dd = row >> 4, s = row & 15;
        int dcl = (d0 + dd < DI) ? d0 + dd : DI-1;
        float a = -__expf(A_log[dcl*DS + s]);
        float carry = 0.f;
        #pragma unroll
        for (int seg = 0; seg < NC/64; seg++) {
            int c = seg*64 + lane;
            float g = __expf(a * sd[dd][c]);
            float H = tile[row][c];
            #pragma unroll
            for (int off = 1; off < 64; off <<= 1) {
                float gp = __shfl_up(g, off);
                float Hp = __shfl_up(H, off);
                if (lane >= off) { H = fmaf(g, Hp, H); g *= gp; }
            }
            float Gx = (lane == 0) ? 1.f : __shfl_up(g, 1);
            float Hx = (lane == 0) ? 0.f : __shfl_up(H, 1);
            tile[row][c] = fmaf(Gx, carry, Hx);   // hinit for chunk c
            float Gl = __shfl(g, 63), Hl = __shfl(H, 63);
            carry = fmaf(Gl, carry, Hl);
        }
    }
    __syncthreads();
    for (int r = 0; r < NC/4; r++) {
        int c = r*4 + (tid >> 6);
        int j = tid & 63;
        hinit_ws[((size_t)(b*NC + c)*DIc + d0)*DS + j] = tile[j][c];
    }
}

// Pass 3: re-scan chunk from hinit (dt loaded, not recomputed), fused epilogue.
// Vectorized ds_read_b128 row reads (8 LDS ops/t instead of 32).
__global__ __launch_bounds__(SCT) void scan_final3(
    const float* __restrict__ xi, const float* __restrict__ xdbl,
    const float* __restrict__ xz, const float* __restrict__ A_log,
    const float* __restrict__ dtbuf, const float* __restrict__ Dp,
    const float* __restrict__ hinit_ws, __hip_bfloat16* __restrict__ y) {
    __shared__ __attribute__((aligned(16))) float xb[CT*LROW];
    int tid = threadIdx.x;
    int bc = blockIdx.x;
    int b = bc / NC, c = bc % NC;
    size_t tok0 = (size_t)b*Lv + (size_t)c*CT;
    stage_xdbl(xb, xdbl, tok0, tid, SCT);
    __syncthreads();
    int d = tid;
    if (d >= DIc) return;
    int dp_ = d < DI ? d : DI-1;

    float a[DS];
    const float* ap = A_log + (size_t)dp_*DS;
    #pragma unroll
    for (int s = 0; s < DS; s++) a[s] = -__expf(ap[s]);
    float Dv = Dp[dp_];

    float h[DS];
    const float* hp = hinit_ws + ((size_t)bc*DIc + d)*DS;
    #pragma unroll
    for (int s = 0; s < DS; s++) h[s] = hp[s];

    #pragma unroll 2
    for (int t = 0; t < CT; t++) {
        const float* row = xb + t*LROW;
        size_t tok = tok0 + t;
        float u   = xi[tok*DI + dp_];
        float zv  = xz[tok*N1p + DI + d];
        float dtv = dtbuf[tok*DIc + d];
        float du = dtv * u;
        float Bl[DS], Cl[DS];
        *(float4*)&Bl[0]  = *(const float4*)(row+20);
        *(float4*)&Bl[4]  = *(const float4*)(row+24);
        *(float4*)&Bl[8]  = *(const float4*)(row+28);
        *(float4*)&Bl[12] = *(const float4*)(row+32);
        *(float4*)&Cl[0]  = *(const float4*)(row+36);
        *(float4*)&Cl[4]  = *(const float4*)(row+40);
        *(float4*)&Cl[8]  = *(const float4*)(row+44);
        *(float4*)&Cl[12] = *(const float4*)(row+48);
        float yv0 = 0.f, yv1 = 0.f;
        #pragma unroll
        for (int s = 0; s < DS; s += 2) {
            h[s]   = fmaf(__expf(dtv*a[s]),   h[s],   du*Bl[s]);
            h[s+1] = fmaf(__expf(dtv*a[s+1]), h[s+1], du*Bl[s+1]);
            yv0 = fmaf(h[s],   Cl[s],   yv0);
            yv1 = fmaf(h[s+1], Cl[s+1], yv1);
        }
        float yv = yv0 + yv1 + u*Dv;
        float g = zv / (1.f + __expf(-zv));
        y[tok*DIp + d] = __float2bfloat16(yv * g);
    }
}

extern "C" void kernel_launch(void* const* d_in, const int* in_sizes, int n_in,
                              void* d_out, int out_size, void* d_ws, size_t ws_size,
                              hipStream_t stream) {
    const float* fuse   = (const float*)d_in[0];
    const float* norm_w = (const float*)d_in[1];
    const float* in_w   = (const float*)d_in[2];
    const float* conv_w = (const float*)d_in[3];
    const float* conv_b = (const float*)d_in[4];
    const float* xp_w   = (const float*)d_in[5];
    const float* dt_w   = (const float*)d_in[6];
    const float* dt_b   = (const float*)d_in[7];
    const float* A_log  = (const float*)d_in[8];
    const float* D_par  = (const float*)d_in[9];
    const float* out_w  = (const float*)d_in[10];
    const float* fn_w   = (const float*)d_in[11];

    char* p = (char*)d_ws;
    auto alloc = [&](size_t bytes) { char* r = p; p += (bytes + 255) & ~(size_t)255; return r; };

    float*          x     = (float*)         alloc((size_t)TOK*DMp*4);
    __hip_bfloat16* xn    = (__hip_bfloat16*)alloc((size_t)TOK*DMp*2);
    float*          xz    = (float*)         alloc((size_t)TOK*N1p*4);
    float*          xi_f  = (float*)         alloc((size_t)TOK*DI*4);
    __hip_bfloat16* xi_b  = (__hip_bfloat16*)alloc((size_t)TOK*DIp*2);
    float*          xdbl  = (float*)         alloc((size_t)TOK*XDp*4);
    __hip_bfloat16* y     = (__hip_bfloat16*)alloc((size_t)TOK*DIp*2);
    float*          dtbuf = (float*)         alloc((size_t)TOK*DIc*4);
    float*          sumdt = (float*)         alloc((size_t)NCB*DIc*4);
    float*          Hws   = (float*)         alloc((size_t)NCB*DIc*DS*4);
    float*          hinit = (float*)         alloc((size_t)NCB*DIc*DS*4);
    __hip_bfloat16* W1b   = (__hip_bfloat16*)alloc((size_t)NL*N1p*DMp*2);
    __hip_bfloat16* W2b   = (__hip_bfloat16*)alloc((size_t)NL*XDp*DIp*2);
    __hip_bfloat16* W3b   = (__hip_bfloat16*)alloc((size_t)NL*N3p*DIp*2);

    {
        int t1 = NL*N1p*DMp, t2 = NL*XDp*DIp, t3 = NL*N3p*DIp;
        cvt_pad_kernel<<<(t1+255)/256, 256, 0, stream>>>(W1b, in_w, 2*DI, DM, N1p, DMp, t1);
        cvt_pad_kernel<<<(t2+255)/256, 256, 0, stream>>>(W2b, xp_w, DTR+2*DS, DI, XDp, DIp, t2);
        cvt_pad_kernel<<<(t3+255)/256, 256, 0, stream>>>(W3b, out_w, DM, DI, N3p, DIp, t3);
        int tz = 2*TOK*(DIp-DI);
        zero_pads_kernel<<<(tz+255)/256, 256, 0, stream>>>(xi_b, y);
    }

    for (int i = 0; i < NL; i++) {
        const __hip_bfloat16* w1 = W1b + (size_t)i*N1p*DMp;
        const __hip_bfloat16* w2 = W2b + (size_t)i*XDp*DIp;
        const __hip_bfloat16* w3 = W3b + (size_t)i*N3p*DIp;
        const float* cw   = conv_w + (size_t)i*DI*DC;
        const float* cb   = conv_b + (size_t)i*DI;
        const float* dtw  = dt_w   + (size_t)i*DI*DTR;
        const float* dtb  = dt_b   + (size_t)i*DI;
        const float* alog = A_log  + (size_t)i*DI*DS;
        const float* dp   = D_par  + (size_t)i*DI;
        const float* nw   = norm_w + (size_t)i*DM;
        const float* xcur = (i == 0) ? fuse : x;
        int ld_cur = (i == 0) ? DM : DMp;

        rmsnorm_kernel<<<TOK, 256, 0, stream>>>(xn, xcur, ld_cur, nw);
        gemm_bf16<<<dim3(N1p/128, TOK/128), 256, 0, stream>>>(
            xn, DMp, w1, DMp, xz, N1p, N1p, nullptr, 0, DMp);
        conv_silu_kernel<<<(TOK*DI + 255)/256, 256, 0, stream>>>(xi_f, xi_b, xz, cw, cb);
        gemm_bf16<<<dim3(XDp/128, TOK/128), 256, 0, stream>>>(
            xi_b, DIp, w2, DIp, xdbl, XDp, XDp, nullptr, 0, DIp);
        // chunked parallel scan (dt fused into pass 1, LDS-transpose combine)
        scan_chunk3<<<NCB, SCT, 0, stream>>>(xi_f, xdbl, alog, dtw, dtb, dtbuf, sumdt, Hws);
        scan_combine_lds<<<dim3(DIc/RD, Bv), 256, 0, stream>>>(sumdt, Hws, alog, hinit);
        scan_final3<<<NCB, SCT, 0, stream>>>(xi_f, xdbl, xz, alog, dtbuf, dp, hinit, y);
        gemm_bf16<<<dim3(N3p/128, TOK/128), 256, 0, stream>>>(
            y, DIp, w3, DIp, x, DMp, DM, xcur, ld_cur, DIp);
    }

    final_kernel<<<TOK, 256, 0, stream>>>((float*)d_out, x, fuse, fn_w);
}